// Round 1
// baseline (1168.599 us; speedup 1.0000x reference)
//
#include <hip/hip_runtime.h>
#include <hip/hip_bf16.h>
#include <math.h>

#define N_SEQ 1024
#define CS 384
#define CZ 128
#define NH 16
#define CH 24

typedef float  floatx4 __attribute__((ext_vector_type(4)));
typedef short  shortx8 __attribute__((ext_vector_type(8)));
typedef unsigned int uintx4 __attribute__((ext_vector_type(4)));

__device__ __forceinline__ unsigned short f2bf(float f){
  union { float fv; unsigned u; } c; c.fv = f;
  unsigned u = c.u;
  return (unsigned short)((u + 0x7fffu + ((u >> 16) & 1u)) >> 16);
}
__device__ __forceinline__ float bf2f(unsigned short s){
  union { unsigned u; float fv; } c; c.u = ((unsigned)s) << 16; return c.fv;
}
__device__ __forceinline__ float bf_lo(unsigned u){
  union { unsigned uu; float f; } c; c.uu = u << 16; return c.f;
}
__device__ __forceinline__ float bf_hi(unsigned u){
  union { unsigned uu; float f; } c; c.uu = u & 0xffff0000u; return c.f;
}
__device__ __forceinline__ float sigmoidf_(float x){ return 1.f / (1.f + __expf(-x)); }

// ---------------- K1: LayerNorm of a_i and s_i (per row) ----------------
__global__ __launch_bounds__(128) void ln_kernel(
    const float* __restrict__ a_i, const float* __restrict__ s_i,
    const float* __restrict__ lns_w,
    float* __restrict__ a_ln, float* __restrict__ s_ln)
{
  int i = blockIdx.x;
  int t = threadIdx.x;
  float av[3], sv[3];
  float sa = 0.f, qa = 0.f, ss = 0.f, qs = 0.f;
  #pragma unroll
  for (int e = 0; e < 3; ++e){
    int c = t + 128*e;
    float a = a_i[(size_t)i*CS + c];
    float s = s_i[(size_t)i*CS + c];
    av[e] = a; sv[e] = s;
    sa += a; qa += a*a; ss += s; qs += s*s;
  }
  #pragma unroll
  for (int off = 1; off < 64; off <<= 1){
    sa += __shfl_xor(sa, off);
    qa += __shfl_xor(qa, off);
    ss += __shfl_xor(ss, off);
    qs += __shfl_xor(qs, off);
  }
  __shared__ float red[2][4];
  if ((t & 63) == 0){
    int w = t >> 6;
    red[w][0] = sa; red[w][1] = qa; red[w][2] = ss; red[w][3] = qs;
  }
  __syncthreads();
  const float inv = 1.f / CS;
  float Sa = red[0][0] + red[1][0];
  float Qa = red[0][1] + red[1][1];
  float Ss = red[0][2] + red[1][2];
  float Qs = red[0][3] + red[1][3];
  float ma = Sa*inv, va = Qa*inv - ma*ma, ra = rsqrtf(va + 1e-5f);
  float ms = Ss*inv, vs = Qs*inv - ms*ms, rs = rsqrtf(vs + 1e-5f);
  #pragma unroll
  for (int e = 0; e < 3; ++e){
    int c = t + 128*e;
    a_ln[(size_t)i*CS + c] = (av[e] - ma) * ra;
    s_ln[(size_t)i*CS + c] = (sv[e] - ms) * rs * lns_w[c];
  }
}

// ---------------- generic small GEMM: 4 rows/block, up to 2 matrices sharing X
// mode 0: OUT1 = sigmoid(X@W1 + B1) * extra + X@W2            (AdaLN)
// mode 1: OUT1 = X@W1 + B1 ; OUT2 = X@W2                      (q,k)
// mode 2: OUT1 = X@W1      ; OUT2 = sigmoid(X@W2)             (v,g)
// mode 3: OUT1 = X@W1                                         (att@wo)
// mode 4: OUT1 = sigmoid(X@W1 + B1) * extra                   (final gate)
__global__ __launch_bounds__(384) void gemm_kernel(
    const float* __restrict__ X, const float* __restrict__ W1,
    const float* __restrict__ B1, const float* __restrict__ W2,
    const float* __restrict__ extra,
    float* __restrict__ OUT1, float* __restrict__ OUT2, int mode)
{
  int r0 = blockIdx.x * 4;
  int t  = threadIdx.x;
  int ct = t % 96;
  int rg = t / 96;
  int c0 = ct * 4;
  __shared__ float xl[4][CS];
  #pragma unroll
  for (int rr = 0; rr < 4; ++rr)
    xl[rr][t] = X[(size_t)(r0+rr)*CS + t];
  __syncthreads();
  float acc1[4] = {0.f,0.f,0.f,0.f};
  float acc2[4] = {0.f,0.f,0.f,0.f};
  if (mode <= 2){
    for (int k = 0; k < CS; k += 4){
      floatx4 s4 = *(const floatx4*)&xl[rg][k];
      #pragma unroll
      for (int kk = 0; kk < 4; ++kk){
        floatx4 w1 = *(const floatx4*)&W1[(size_t)(k+kk)*CS + c0];
        floatx4 w2 = *(const floatx4*)&W2[(size_t)(k+kk)*CS + c0];
        #pragma unroll
        for (int cc = 0; cc < 4; ++cc){
          acc1[cc] += s4[kk] * w1[cc];
          acc2[cc] += s4[kk] * w2[cc];
        }
      }
    }
  } else {
    for (int k = 0; k < CS; k += 4){
      floatx4 s4 = *(const floatx4*)&xl[rg][k];
      #pragma unroll
      for (int kk = 0; kk < 4; ++kk){
        floatx4 w1 = *(const floatx4*)&W1[(size_t)(k+kk)*CS + c0];
        #pragma unroll
        for (int cc = 0; cc < 4; ++cc)
          acc1[cc] += s4[kk] * w1[cc];
      }
    }
  }
  int r = r0 + rg;
  size_t ob = (size_t)r * CS + c0;
  if (mode == 0){
    #pragma unroll
    for (int cc = 0; cc < 4; ++cc)
      OUT1[ob+cc] = sigmoidf_(acc1[cc] + B1[c0+cc]) * extra[ob+cc] + acc2[cc];
  } else if (mode == 1){
    #pragma unroll
    for (int cc = 0; cc < 4; ++cc){
      OUT1[ob+cc] = acc1[cc] + B1[c0+cc];
      OUT2[ob+cc] = acc2[cc];
    }
  } else if (mode == 2){
    #pragma unroll
    for (int cc = 0; cc < 4; ++cc){
      OUT1[ob+cc] = acc1[cc];
      OUT2[ob+cc] = sigmoidf_(acc2[cc]);
    }
  } else if (mode == 3){
    #pragma unroll
    for (int cc = 0; cc < 4; ++cc)
      OUT1[ob+cc] = acc1[cc];
  } else {
    #pragma unroll
    for (int cc = 0; cc < 4; ++cc)
      OUT1[ob+cc] = sigmoidf_(acc1[cc] + B1[c0+cc]) * extra[ob+cc];
  }
}

// ---------------- K4: pair bias via MFMA ----------------
// bias[h][i][j] = rstd*(dot(z, lnb_w*wb[:,h]) - mean*sumw[h]) + sumb[h], stored bf16
// One wave handles 16 pairs (consecutive j). A-frag = z (bf16), B-frag = lnb_w*wb.
__global__ __launch_bounds__(256) void bias_kernel(
    const float* __restrict__ z, const float* __restrict__ lnb_w,
    const float* __restrict__ lnb_b, const float* __restrict__ wb,
    unsigned short* __restrict__ bias)
{
  int i    = blockIdx.x >> 4;
  int j0   = (blockIdx.x & 15) * 64;
  int wave = threadIdx.x >> 6;
  int lane = threadIdx.x & 63;
  int m    = lane & 15;   // A-row (pair) for loads; also D-col (head) for epilogue
  int q    = lane >> 4;   // quad
  int jbase = j0 + wave * 16;

  // B fragments (constant weights) + per-head sums (fp32)
  shortx8 bfrag[4];
  float sumw = 0.f, sumb = 0.f;
  #pragma unroll
  for (int s = 0; s < 4; ++s){
    #pragma unroll
    for (int jj = 0; jj < 8; ++jj){
      int c = q*8 + jj + 32*s;
      float lw = lnb_w[c];
      float lb = lnb_b[c];
      float w  = wb[c*NH + m];
      bfrag[s][jj] = (short)f2bf(lw * w);
      sumw += lw * w;
      sumb += lb * w;
    }
  }
  sumw += __shfl_xor(sumw, 16); sumw += __shfl_xor(sumw, 32);
  sumb += __shfl_xor(sumb, 16); sumb += __shfl_xor(sumb, 32);

  const float* zrow = z + ((size_t)i * N_SEQ + (size_t)(jbase + m)) * CZ;
  floatx4 acc = {0.f, 0.f, 0.f, 0.f};
  float sum = 0.f, sq = 0.f;
  #pragma unroll
  for (int s = 0; s < 4; ++s){
    floatx4 z0 = *(const floatx4*)(zrow + q*8 + 32*s);
    floatx4 z1 = *(const floatx4*)(zrow + q*8 + 32*s + 4);
    shortx8 af;
    #pragma unroll
    for (int e = 0; e < 4; ++e){
      sum += z0[e]; sq += z0[e]*z0[e];
      sum += z1[e]; sq += z1[e]*z1[e];
      af[e]   = (short)f2bf(z0[e]);
      af[e+4] = (short)f2bf(z1[e]);
    }
    acc = __builtin_amdgcn_mfma_f32_16x16x32_bf16(af, bfrag[s], acc, 0, 0, 0);
  }
  // stats for pair m live in lanes {m, m+16, m+32, m+48}
  sum += __shfl_xor(sum, 16); sum += __shfl_xor(sum, 32);
  sq  += __shfl_xor(sq , 16); sq  += __shfl_xor(sq , 32);
  float mean = sum * (1.f/CZ);
  float var  = sq  * (1.f/CZ) - mean*mean;
  float rstd = rsqrtf(var + 1e-5f);

  __shared__ float ob[NH][65];
  #pragma unroll
  for (int r = 0; r < 4; ++r){
    int row = q*4 + r;                 // D row = pair
    float mr = __shfl(mean, row);      // stats held by lane 'row'
    float rr = __shfl(rstd, row);
    ob[m][wave*16 + row] = rr * (acc[r] - mr * sumw) + sumb;
  }
  __syncthreads();
  size_t base = (size_t)i * N_SEQ + j0;
  #pragma unroll
  for (int rep = 0; rep < 4; ++rep){
    int idx = threadIdx.x + rep*256;
    int hh = idx >> 6;
    int jj = idx & 63;
    bias[(size_t)hh * ((size_t)N_SEQ*N_SEQ) + base + jj] = f2bf(ob[hh][jj]);
  }
}

// ---------------- K5: fused attention (no max-tracking: logits bounded ~|1.5|)
#define TJ 128
#define KROW 20  // uint words per LDS row (12 used, pad breaks 4-way bank conflicts)
__global__ __launch_bounds__(256) void attn_kernel(
    const float* __restrict__ qq, const float* __restrict__ kk,
    const float* __restrict__ vv, const float* __restrict__ gg,
    const unsigned short* __restrict__ bias, float* __restrict__ att)
{
  int h  = blockIdx.x & 15;
  int i0 = (blockIdx.x >> 4) * 16;
  int il = threadIdx.x & 15;
  int jg = threadIdx.x >> 4;

  __shared__ unsigned int smem[TJ*KROW*2];   // k tile | v tile (bf16x2 packed); reused for merge

  float qr[24];
  {
    const float* qs = qq + (size_t)(i0+il)*CS + h*CH;
    #pragma unroll
    for (int e = 0; e < 6; ++e){
      floatx4 t4 = *(const floatx4*)(qs + 4*e);
      qr[4*e] = t4[0]; qr[4*e+1] = t4[1]; qr[4*e+2] = t4[2]; qr[4*e+3] = t4[3];
    }
  }
  const float scale = 0.20412414523193154f; // 1/sqrt(24)
  float lrun = 0.f;
  float o[24];
  #pragma unroll
  for (int d = 0; d < 24; ++d) o[d] = 0.f;

  for (int jt = 0; jt < 8; ++jt){
    __syncthreads();
    {
      int row  = threadIdx.x >> 1;
      int half = threadIdx.x & 1;
      const float* ks = kk + (size_t)(jt*TJ + row)*CS + h*CH + half*12;
      const float* vs = vv + (size_t)(jt*TJ + row)*CS + h*CH + half*12;
      unsigned int* kd = smem + row*KROW + half*6;
      unsigned int* vd = smem + TJ*KROW + row*KROW + half*6;
      #pragma unroll
      for (int e = 0; e < 6; ++e){
        kd[e] = (unsigned)f2bf(ks[2*e]) | ((unsigned)f2bf(ks[2*e+1]) << 16);
        vd[e] = (unsigned)f2bf(vs[2*e]) | ((unsigned)f2bf(vs[2*e+1]) << 16);
      }
    }
    __syncthreads();
    const unsigned short* bptr = bias + (size_t)h*((size_t)N_SEQ*N_SEQ)
                               + (size_t)(i0+il)*N_SEQ + jt*TJ;
    #pragma unroll
    for (int tt = 0; tt < 8; ++tt){
      int jl = jg + 16*tt;
      uintx4 k0 = *(const uintx4*)&smem[jl*KROW];
      uintx4 k1 = *(const uintx4*)&smem[jl*KROW + 4];
      uintx4 k2 = *(const uintx4*)&smem[jl*KROW + 8];
      float dot = 0.f;
      #pragma unroll
      for (int e = 0; e < 4; ++e){
        dot += bf_lo(k0[e])*qr[2*e]      + bf_hi(k0[e])*qr[2*e+1];
        dot += bf_lo(k1[e])*qr[8+2*e]    + bf_hi(k1[e])*qr[8+2*e+1];
        dot += bf_lo(k2[e])*qr[16+2*e]   + bf_hi(k2[e])*qr[16+2*e+1];
      }
      float p = __expf(dot * scale + bf2f(bptr[jl]));
      lrun += p;
      uintx4 v0 = *(const uintx4*)&smem[TJ*KROW + jl*KROW];
      uintx4 v1 = *(const uintx4*)&smem[TJ*KROW + jl*KROW + 4];
      uintx4 v2 = *(const uintx4*)&smem[TJ*KROW + jl*KROW + 8];
      #pragma unroll
      for (int e = 0; e < 4; ++e){
        o[2*e]      += p * bf_lo(v0[e]);  o[2*e+1]    += p * bf_hi(v0[e]);
        o[8+2*e]    += p * bf_lo(v1[e]);  o[8+2*e+1]  += p * bf_hi(v1[e]);
        o[16+2*e]   += p * bf_lo(v2[e]);  o[16+2*e+1] += p * bf_hi(v2[e]);
      }
    }
  }
  __syncthreads();
  // reduce the 4 jg-groups inside each wave (lanes with same il)
  #pragma unroll
  for (int d = 0; d < 24; ++d){
    o[d] += __shfl_xor(o[d], 16);
    o[d] += __shfl_xor(o[d], 32);
  }
  lrun += __shfl_xor(lrun, 16);
  lrun += __shfl_xor(lrun, 32);
  float* mgf = (float*)smem;
  int lane = threadIdx.x & 63;
  int w    = threadIdx.x >> 6;
  if (lane < 16){
    float* slot = mgf + (w*16 + lane)*25;
    slot[0] = lrun;
    #pragma unroll
    for (int d = 0; d < 24; ++d) slot[1+d] = o[d];
  }
  __syncthreads();
  if (threadIdx.x < 16){
    int ii = threadIdx.x;
    float L = 0.f, O[24];
    #pragma unroll
    for (int d = 0; d < 24; ++d) O[d] = 0.f;
    for (int w2 = 0; w2 < 4; ++w2){
      const float* slot = mgf + (w2*16 + ii)*25;
      L += slot[0];
      #pragma unroll
      for (int d = 0; d < 24; ++d) O[d] += slot[1+d];
    }
    const float* gs = gg + (size_t)(i0+ii)*CS + h*CH;
    float* os = att + (size_t)(i0+ii)*CS + h*CH;
    float invL = 1.f / L;
    #pragma unroll
    for (int d = 0; d < 24; ++d) os[d] = O[d] * invL * gs[d];
  }
}

extern "C" void kernel_launch(void* const* d_in, const int* in_sizes, int n_in,
                              void* d_out, int out_size, void* d_ws, size_t ws_size,
                              hipStream_t stream) {
  const float* a_i     = (const float*)d_in[0];
  const float* s_i     = (const float*)d_in[1];
  const float* z_ij    = (const float*)d_in[2];
  const float* lns_w   = (const float*)d_in[3];
  const float* ada_ws  = (const float*)d_in[4];
  const float* ada_bs  = (const float*)d_in[5];
  const float* ada_wns = (const float*)d_in[6];
  const float* wq      = (const float*)d_in[7];
  const float* bq      = (const float*)d_in[8];
  const float* wk      = (const float*)d_in[9];
  const float* wv      = (const float*)d_in[10];
  const float* lnb_w   = (const float*)d_in[11];
  const float* lnb_b   = (const float*)d_in[12];
  const float* wb      = (const float*)d_in[13];
  const float* wg      = (const float*)d_in[14];
  const float* wo      = (const float*)d_in[15];
  const float* wsm     = (const float*)d_in[16];
  const float* bsv     = (const float*)d_in[17];

  const size_t RC = (size_t)N_SEQ * CS;   // 393216
  float* wsf  = (float*)d_ws;
  float* s_ln = wsf;
  float* a_ln = wsf + RC;
  float* a    = wsf + 2*RC;
  float* qv   = wsf + 3*RC;
  float* kv   = wsf + 4*RC;
  float* vvp  = wsf + 5*RC;
  float* gv   = wsf + 6*RC;
  float* attb = wsf + 7*RC;
  float* tmp  = wsf + 8*RC;
  unsigned short* biasw = (unsigned short*)(wsf + 9*RC);  // 16*1024*1024 bf16 = 32 MB

  ln_kernel<<<N_SEQ, 128, 0, stream>>>(a_i, s_i, lns_w, a_ln, s_ln);
  gemm_kernel<<<N_SEQ/4, 384, 0, stream>>>(s_ln, ada_ws, ada_bs, ada_wns, a_ln, a, nullptr, 0);
  gemm_kernel<<<N_SEQ/4, 384, 0, stream>>>(a, wq, bq, wk, nullptr, qv, kv, 1);
  gemm_kernel<<<N_SEQ/4, 384, 0, stream>>>(a, wv, nullptr, wg, nullptr, vvp, gv, 2);
  bias_kernel<<<N_SEQ*16, 256, 0, stream>>>(z_ij, lnb_w, lnb_b, wb, biasw);
  attn_kernel<<<N_SEQ, 256, 0, stream>>>(qv, kv, vvp, gv, biasw, attb);
  gemm_kernel<<<N_SEQ/4, 384, 0, stream>>>(attb, wo, nullptr, nullptr, nullptr, tmp, nullptr, 3);
  gemm_kernel<<<N_SEQ/4, 384, 0, stream>>>(s_i, wsm, bsv, nullptr, tmp, (float*)d_out, nullptr, 4);
}